// Round 6
// baseline (302.832 us; speedup 1.0000x reference)
//
#include <hip/hip_runtime.h>

#define N_NODES 50000
#define N_EDGES 600000
#define C 128
#define STRIPS 3125          // N_NODES / 16
#define MLP_WAVES 1024       // 256 blocks x 4 waves; wave owns weight-set wid&3

typedef __bf16 bf16;
typedef __attribute__((ext_vector_type(8))) __bf16 bf16x8;
typedef __attribute__((ext_vector_type(4))) __bf16 bf16x4;
typedef __attribute__((ext_vector_type(2))) __bf16 bf16x2;
typedef __attribute__((ext_vector_type(4))) float f32x4;
typedef __attribute__((ext_vector_type(2))) float f32x2;

struct PtrsV { const void* p[8]; };

// ---------------------------------------------------------------------------
// Dtype detection (verified R2-R5): flags 1 = fp32, 0 = bf16.
// Merged with deg-zeroing to save a dispatch: block 0 = detect, blocks 1..196
// zero deg[50000].
// ---------------------------------------------------------------------------
__device__ __forceinline__ int bf16_wild(unsigned short w) {
    int exp = (w >> 7) & 0xFF;
    int mant = w & 0x7F;
    if (exp == 0xFF) return 1;
    if (exp >= 133) return 1;                // |x| >= 64
    if (exp == 0) return mant != 0 ? 1 : 0;  // denormal
    if (exp <= 114) return 1;                // 0 < |x| < 2^-12
    return 0;
}

__global__ void __launch_bounds__(256) detect_zero_kernel(
    const unsigned short* __restrict__ emb,
    const unsigned short* __restrict__ w,
    const unsigned short* __restrict__ b,
    const unsigned short* __restrict__ hc,
    int* __restrict__ flags, int* __restrict__ deg)
{
    if (blockIdx.x == 0) {
        int lane = threadIdx.x;
        if (lane >= 64) return;
        int ce = 0, cw = 0, cb = 0, ch = 0;
        for (int j = 0; j < 4; ++j) {
            ce += bf16_wild(emb[lane * 4 + j]);
            cw += bf16_wild(w[lane * 4 + j]);
        }
        for (int j = 0; j < 2; ++j) cb += bf16_wild(b[lane * 2 + j]);
        if (lane < 3) ch = bf16_wild(hc[lane]);
        for (int off = 32; off > 0; off >>= 1) {
            ce += __shfl_down(ce, off);
            cw += __shfl_down(cw, off);
            cb += __shfl_down(cb, off);
            ch += __shfl_down(ch, off);
        }
        if (lane == 0) {
            int wf = (cw >= 16) ? 1 : 0;
            flags[0] = (ce >= 16) ? 1 : 0;
            flags[1] = wf;
            flags[2] = (cb >= 8) ? 1 : 0;
            flags[3] = (ch > 0) ? 1 : wf;
        }
    } else {
        int i = (blockIdx.x - 1) * 256 + threadIdx.x;
        if (i < N_NODES) deg[i] = 0;
    }
}

// ---------------------------------------------------------------------------
// Pack weights into MFMA B-fragment order (verified R2-R5).
// Element index within matrix = kk*4096 + n0*512 + lane*8 + j.
// Slots 4,5 are the second hh matrix (+16384 elems / +128 bias).
// ---------------------------------------------------------------------------
__global__ void __launch_bounds__(256) pack_kernel(
    PtrsV wmats, PtrsV bvecs, const void* hc_raw,
    const int* __restrict__ flags,
    bf16* __restrict__ pw, float* __restrict__ cbias, float* __restrict__ ccoef)
{
    int tid = blockIdx.x * 256 + threadIdx.x;
    int wf = flags[1], bfl = flags[2], hf = flags[3];
    if (tid < 8 * 16384) {
        int m    = tid >> 14;
        int r    = tid & 16383;
        int j    = r & 7;
        int lane = (r >> 3) & 63;
        int n0   = (r >> 9) & 7;
        int kk   = r >> 12;
        int k = kk * 32 + (lane >> 4) * 8 + j;
        int n = n0 * 16 + (lane & 15);
        int idx = k * C + n + ((m == 4 || m == 5) ? 16384 : 0);
        float v = wf ? ((const float*)wmats.p[m])[idx]
                     : (float)((const bf16*)wmats.p[m])[idx];
        pw[tid] = (bf16)v;
    } else if (tid < 8 * 16384 + 1024) {
        int j = tid - 8 * 16384;
        int m = j >> 7, n = j & 127;
        int idx = n + ((m == 4 || m == 5) ? 128 : 0);
        float v = bfl ? ((const float*)bvecs.p[m])[idx]
                      : (float)((const bf16*)bvecs.p[m])[idx];
        cbias[j] = v;
    } else if (tid < 8 * 16384 + 1024 + 3) {
        int i = tid - (8 * 16384 + 1024);
        float v = hf ? ((const float*)hc_raw)[i]
                     : (float)((const bf16*)hc_raw)[i];
        ccoef[i] = v;
    }
}

// ---------------------------------------------------------------------------
// MLP v3: weights live in VGPRs. 1024 waves; wave wid owns weight-set wid&3
// (0 rel, 1 hh0, 2 hh1, 3 loop) and grid-strides strips wid>>2, +256, ...
// Inner loop: zero weight loads, 64 MFMA, A prefetched one strip ahead.
// __launch_bounds__(256,1): 1 wave/SIMD -> up to 512 VGPRs (need ~380).
// ---------------------------------------------------------------------------
__global__ __launch_bounds__(256, 1) void mlp_kernel(
    const void* __restrict__ emb_raw,    // [3][N][C] fp32 or bf16
    const bf16* __restrict__ pw,         // packed weights [8][16384]
    const float* __restrict__ cbias,     // [8][128]
    const float* __restrict__ ccoef,     // [3]
    const int* __restrict__ flags,
    bf16* __restrict__ h,                // [3][N][C], premultiplied by coef
    bf16* __restrict__ hs)               // [N][C] self term (loop MLP)
{
    __shared__ bf16 sH[4][16][136];
    const int tid  = threadIdx.x;
    const int wave = tid >> 6, lane = tid & 63;
    const int wid  = blockIdx.x * 4 + wave;   // 0..1023
    const int set  = wid & 3;
    const int wstart = wid >> 2;              // 0..255
    const int lrow = lane & 15, lquad = lane >> 4;
    bf16 (*sh)[136] = sH[wave];

    const int mat1_of[4]  = {0, 2, 4, 6};
    const int layer_of[4] = {2, 1, 0, 2};
    const int m1 = mat1_of[set];
    const bf16x8* w1v = (const bf16x8*)(pw + (size_t)m1 * 16384);
    const bf16x8* w2v = w1v + 2048;          // next matrix
    const float* b1 = cbias + m1 * 128;
    const float* b2 = b1 + 128;
    const float oscale = (set == 0) ? ccoef[0] : (set == 1) ? ccoef[1]
                       : (set == 2) ? ccoef[2] : 1.0f;
    bf16* outp = (set == 3) ? hs : (h + (size_t)set * N_NODES * C);
    const int emb_f32 = flags[0];
    const size_t lbase = (size_t)layer_of[set] * N_NODES * C;

    // ---- preload both weight matrices' B-fragments + biases into registers ----
    bf16x8 W1f[8][4], W2f[8][4];
    #pragma unroll
    for (int n0 = 0; n0 < 8; ++n0)
        #pragma unroll
        for (int kk = 0; kk < 4; ++kk) {
            W1f[n0][kk] = w1v[kk * 512 + n0 * 64 + lane];
            W2f[n0][kk] = w2v[kk * 512 + n0 * 64 + lane];
        }
    float b1f[8], b2f[8];
    #pragma unroll
    for (int n0 = 0; n0 < 8; ++n0) {
        b1f[n0] = b1[n0 * 16 + lrow];
        b2f[n0] = b2[n0 * 16 + lrow];
    }

    // A-frag loader: A[m=lane&15][k=quad*8+j]
    auto loadA = [&](int strip, bf16x8 af[4]) {
        size_t xb = lbase + (size_t)(strip * 16 + lrow) * C + lquad * 8;
        if (emb_f32) {
            const float* xf = (const float*)emb_raw + xb;
            #pragma unroll
            for (int kk = 0; kk < 4; ++kk) {
                f32x4 u0 = *(const f32x4*)(xf + kk * 32);
                f32x4 u1 = *(const f32x4*)(xf + kk * 32 + 4);
                bf16x8 v;
                v[0]=(bf16)u0[0]; v[1]=(bf16)u0[1]; v[2]=(bf16)u0[2]; v[3]=(bf16)u0[3];
                v[4]=(bf16)u1[0]; v[5]=(bf16)u1[1]; v[6]=(bf16)u1[2]; v[7]=(bf16)u1[3];
                af[kk] = v;
            }
        } else {
            const bf16* x16 = (const bf16*)emb_raw + xb;
            #pragma unroll
            for (int kk = 0; kk < 4; ++kk)
                af[kk] = *(const bf16x8*)(x16 + kk * 32);
        }
    };

    bf16x8 af[4];
    if (wstart < STRIPS) loadA(wstart, af);
    for (int s = wstart; s < STRIPS; s += 256) {
        // ---- GEMM1: hidden = relu(X @ W1 + b1) -> sh ----
        #pragma unroll
        for (int n0 = 0; n0 < 8; ++n0) {
            f32x4 a4 = {0.f, 0.f, 0.f, 0.f};
            #pragma unroll
            for (int kk = 0; kk < 4; ++kk)
                a4 = __builtin_amdgcn_mfma_f32_16x16x32_bf16(af[kk], W1f[n0][kk], a4, 0, 0, 0);
            float bias = b1f[n0];
            int n = n0 * 16 + lrow;
            #pragma unroll
            for (int r = 0; r < 4; ++r) {
                float v = a4[r] + bias;
                v = v > 0.f ? v : 0.f;
                sh[lquad * 4 + r][n] = (bf16)v;
            }
        }
        // ---- prefetch next strip's A while GEMM2 runs ----
        bf16x8 afn[4];
        int snext = s + 256;
        if (snext < STRIPS) loadA(snext, afn);
        // ---- GEMM2 A-frags from sh (in-wave DS ordering; verified R5) ----
        bf16x8 ah[4];
        #pragma unroll
        for (int kk = 0; kk < 4; ++kk)
            ah[kk] = *(const bf16x8*)(&sh[lrow][kk * 32 + lquad * 8]);
        #pragma unroll
        for (int n0 = 0; n0 < 8; ++n0) {
            f32x4 a4 = {0.f, 0.f, 0.f, 0.f};
            #pragma unroll
            for (int kk = 0; kk < 4; ++kk)
                a4 = __builtin_amdgcn_mfma_f32_16x16x32_bf16(ah[kk], W2f[n0][kk], a4, 0, 0, 0);
            float bias = b2f[n0];
            int n = n0 * 16 + lrow;
            #pragma unroll
            for (int r = 0; r < 4; ++r)
                sh[lquad * 4 + r][n] = (bf16)((a4[r] + bias) * oscale);
        }
        // ---- coalesced store of the 16x128 strip ----
        {
            int row = lane >> 2;
            int cs  = (lane & 3) * 32;
            bf16* dst = outp + (size_t)(s * 16) * C;
            #pragma unroll
            for (int i = 0; i < 4; ++i) {
                bf16x8 v = *(const bf16x8*)(&sh[row][cs + i * 8]);
                *(bf16x8*)(dst + (size_t)row * C + cs + i * 8) = v;
            }
        }
        #pragma unroll
        for (int kk = 0; kk < 4; ++kk) af[kk] = afn[kk];
    }
}

// ---------------------------------------------------------------------------
// CSR build: histogram, 3-phase scan, bucket fill (verified R5).
// ---------------------------------------------------------------------------
__global__ void __launch_bounds__(256) hist_kernel(
    const int* __restrict__ erow, int* __restrict__ deg)
{
    int e = blockIdx.x * 256 + threadIdx.x;
    if (e >= N_EDGES) return;
    atomicAdd(&deg[erow[e]], 1);
}

__device__ __forceinline__ int wave_incl_scan(int v, int lane) {
    int x = v;
    #pragma unroll
    for (int d = 1; d < 64; d <<= 1) {
        int t = __shfl_up(x, d);
        if (lane >= d) x += t;
    }
    return x;
}

__global__ void __launch_bounds__(256) scanA_kernel(
    const int* __restrict__ deg, int* __restrict__ offsets, int* __restrict__ btot)
{
    __shared__ int swave[4];
    int b = blockIdx.x, tid = threadIdx.x;
    int i = b * 256 + tid;
    int lane = tid & 63, wv = tid >> 6;
    int v = (i < N_NODES) ? deg[i] : 0;
    int x = wave_incl_scan(v, lane);
    if (lane == 63) swave[wv] = x;
    __syncthreads();
    int w0 = swave[0], w1 = swave[1], w2 = swave[2], w3 = swave[3];
    int wp = (wv > 0 ? w0 : 0) + (wv > 1 ? w1 : 0) + (wv > 2 ? w2 : 0);
    if (i < N_NODES) offsets[i] = wp + x - v;
    if (tid == 0) btot[b] = w0 + w1 + w2 + w3;
}

__global__ void __launch_bounds__(256) scanB_kernel(
    const int* __restrict__ btot, int* __restrict__ bbase, int nblk)
{
    __shared__ int swave[4];
    int tid = threadIdx.x;
    int lane = tid & 63, wv = tid >> 6;
    int v = (tid < nblk) ? btot[tid] : 0;
    int x = wave_incl_scan(v, lane);
    if (lane == 63) swave[wv] = x;
    __syncthreads();
    int w0 = swave[0], w1 = swave[1], w2 = swave[2], w3 = swave[3];
    int wp = (wv > 0 ? w0 : 0) + (wv > 1 ? w1 : 0) + (wv > 2 ? w2 : 0);
    if (tid < nblk) bbase[tid] = wp + x - v;
}

__global__ void __launch_bounds__(256) scanC_kernel(
    const int* __restrict__ bbase, int* __restrict__ offsets, int* __restrict__ cursor)
{
    int i = blockIdx.x * 256 + threadIdx.x;
    if (i < N_NODES) {
        int o = offsets[i] + bbase[blockIdx.x];
        offsets[i] = o;
        cursor[i] = o;
    }
    if (i == 0) offsets[N_NODES] = N_EDGES;
}

__global__ void __launch_bounds__(256) fill_kernel(
    const int* __restrict__ erow, const int* __restrict__ ecol,
    const int* __restrict__ ew,
    int* __restrict__ cursor, int* __restrict__ edata)
{
    int e = blockIdx.x * 256 + threadIdx.x;
    if (e >= N_EDGES) return;
    int dst = erow[e];
    int pos = atomicAdd(&cursor[dst], 1);
    edata[pos] = (ecol[e] << 2) | (ew[e] - 1);
}

// ---------------------------------------------------------------------------
// Gather: one wave per node, lane = 2 channels; h coef-premultiplied so the
// inner op is a plain add. 8/4/1 unroll cascade for load ILP.
// ---------------------------------------------------------------------------
__global__ void __launch_bounds__(256) gather_kernel(
    const int* __restrict__ offsets, const int* __restrict__ edata,
    const bf16* __restrict__ h,          // [3][N][C]
    const bf16* __restrict__ hs,         // [N][C]
    void* __restrict__ out,
    const int* __restrict__ flags)
{
    const int node = blockIdx.x * 4 + (threadIdx.x >> 6);
    if (node >= N_NODES) return;
    const int lane = threadIdx.x & 63;
    const int c = lane * 2;

    bf16x2 sv = *(const bf16x2*)(hs + (size_t)node * C + c);
    float a0 = (float)sv[0], a1 = (float)sv[1];

    const int s = offsets[node], e = offsets[node + 1];
    for (int base = s; base < e; base += 64) {
        int idx = base + lane;
        int ed_i = (idx < e) ? edata[idx] : 0;
        int cnt = e - base; if (cnt > 64) cnt = 64;
        int j = 0;
        for (; j + 8 <= cnt; j += 8) {
            float t0 = 0.f, t1 = 0.f;
            #pragma unroll
            for (int u = 0; u < 8; ++u) {
                int ed = __shfl(ed_i, j + u);
                bf16x2 v = *(const bf16x2*)(h + (size_t)(ed & 3) * (N_NODES * C)
                                              + (size_t)(ed >> 2) * C + c);
                t0 += (float)v[0];
                t1 += (float)v[1];
            }
            a0 += t0; a1 += t1;
        }
        for (; j + 4 <= cnt; j += 4) {
            int e0 = __shfl(ed_i, j);
            int e1 = __shfl(ed_i, j + 1);
            int e2 = __shfl(ed_i, j + 2);
            int e3 = __shfl(ed_i, j + 3);
            bf16x2 v0 = *(const bf16x2*)(h + (size_t)(e0 & 3) * (N_NODES * C) + (size_t)(e0 >> 2) * C + c);
            bf16x2 v1 = *(const bf16x2*)(h + (size_t)(e1 & 3) * (N_NODES * C) + (size_t)(e1 >> 2) * C + c);
            bf16x2 v2 = *(const bf16x2*)(h + (size_t)(e2 & 3) * (N_NODES * C) + (size_t)(e2 >> 2) * C + c);
            bf16x2 v3 = *(const bf16x2*)(h + (size_t)(e3 & 3) * (N_NODES * C) + (size_t)(e3 >> 2) * C + c);
            a0 += (float)v0[0] + (float)v1[0] + (float)v2[0] + (float)v3[0];
            a1 += (float)v0[1] + (float)v1[1] + (float)v2[1] + (float)v3[1];
        }
        for (; j < cnt; ++j) {
            int ed = __shfl(ed_i, j);
            bf16x2 v = *(const bf16x2*)(h + (size_t)(ed & 3) * (N_NODES * C) + (size_t)(ed >> 2) * C + c);
            a0 += (float)v[0];
            a1 += (float)v[1];
        }
    }

    if (flags[0]) {
        f32x2 o; o[0] = a0; o[1] = a1;
        *(f32x2*)((float*)out + (size_t)node * C + c) = o;
    } else {
        bf16x2 o; o[0] = (bf16)a0; o[1] = (bf16)a1;
        *(bf16x2*)((bf16*)out + (size_t)node * C + c) = o;
    }
}

// ---------------------------------------------------------------------------
extern "C" void kernel_launch(void* const* d_in, const int* in_sizes, int n_in,
                              void* d_out, int out_size, void* d_ws, size_t ws_size,
                              hipStream_t stream) {
    // 0 t | 1 node_embeddings [3,N,C] | 2 edge_index [2,E] | 3 edge_weights [E]
    // 4 loop_W1 5 loop_b1 6 loop_W2 7 loop_b2 | 8 rel_W1 9 rel_b1 10 rel_W2 11 rel_b2
    // 12 hh_W1 [2,C,C] 13 hh_b1 [2,C] 14 hh_W2 [2,C,C] 15 hh_b2 [2,C] | 16 hop_coef [3]
    const void* emb = d_in[1];
    const int*  ei  = (const int*)d_in[2];
    const int*  ew  = (const int*)d_in[3];

    // ws layout
    const size_t H_BYTES  = (size_t)3 * N_NODES * C * sizeof(bf16);   // 38.4 MB
    const size_t HS_BYTES = (size_t)N_NODES * C * sizeof(bf16);       // 12.8 MB
    const size_t PW_BYTES = (size_t)8 * 16384 * sizeof(bf16);         // 256 KB
    bf16*  h      = (bf16*)d_ws;
    bf16*  hs     = (bf16*)((char*)d_ws + H_BYTES);
    bf16*  pw     = (bf16*)((char*)d_ws + H_BYTES + HS_BYTES);
    float* cbias  = (float*)((char*)d_ws + H_BYTES + HS_BYTES + PW_BYTES);
    float* ccoef  = cbias + 1024;
    int*   flags  = (int*)(ccoef + 4);
    int*   deg    = flags + 16;
    int*   cursor = deg + N_NODES;
    int*   offsets= cursor + N_NODES;
    int*   btot   = offsets + N_NODES + 8;
    int*   bbase  = btot + 256;
    int*   edata  = bbase + 256;

    // pack slots: 0 rel_W1, 1 rel_W2, 2 hh_W1[0], 3 hh_W2[0], 4 hh_W1[1], 5 hh_W2[1], 6 loop_W1, 7 loop_W2
    PtrsV wptr;
    wptr.p[0] = d_in[8];   wptr.p[1] = d_in[10];
    wptr.p[2] = d_in[12];  wptr.p[3] = d_in[14];
    wptr.p[4] = d_in[12];  wptr.p[5] = d_in[14];   // +16384 elems inside pack
    wptr.p[6] = d_in[4];   wptr.p[7] = d_in[6];
    PtrsV bptr;
    bptr.p[0] = d_in[9];   bptr.p[1] = d_in[11];
    bptr.p[2] = d_in[13];  bptr.p[3] = d_in[15];
    bptr.p[4] = d_in[13];  bptr.p[5] = d_in[15];   // +128 inside pack
    bptr.p[6] = d_in[5];   bptr.p[7] = d_in[7];

    const int NBLK = (N_NODES + 255) / 256;   // 196

    detect_zero_kernel<<<1 + NBLK, 256, 0, stream>>>(
        (const unsigned short*)emb, (const unsigned short*)d_in[8],
        (const unsigned short*)d_in[9], (const unsigned short*)d_in[16],
        flags, deg);

    pack_kernel<<<517, 256, 0, stream>>>(wptr, bptr, d_in[16], flags, pw, cbias, ccoef);

    const int* erow = ei;
    const int* ecol = ei + N_EDGES;
    hist_kernel<<<(N_EDGES + 255) / 256, 256, 0, stream>>>(erow, deg);
    scanA_kernel<<<NBLK, 256, 0, stream>>>(deg, offsets, btot);
    scanB_kernel<<<1, 256, 0, stream>>>(btot, bbase, NBLK);
    scanC_kernel<<<NBLK, 256, 0, stream>>>(bbase, offsets, cursor);
    fill_kernel<<<(N_EDGES + 255) / 256, 256, 0, stream>>>(erow, ecol, ew, cursor, edata);

    // MLPs: weights-in-registers, 256 blocks x 4 waves
    mlp_kernel<<<MLP_WAVES / 4, 256, 0, stream>>>(emb, pw, cbias, ccoef, flags, h, hs);

    gather_kernel<<<(N_NODES + 3) / 4, 256, 0, stream>>>(
        offsets, edata, h, hs, d_out, flags);
}

// Round 7
// 285.429 us; speedup vs baseline: 1.0610x; 1.0610x over previous
//
#include <hip/hip_runtime.h>

#define N_NODES 50000
#define N_EDGES 600000
#define C 128
#define STRIPS 3125          // N_NODES / 16
#define GROUPS 782           // ceil(STRIPS/4): 64-node groups per task
#define N_TASKS 4            // 0 rel(L2) 1 hh0(L1) 2 hh1(L0) 3 loop(L2)

typedef __bf16 bf16;
typedef __attribute__((ext_vector_type(8))) __bf16 bf16x8;
typedef __attribute__((ext_vector_type(4))) __bf16 bf16x4;
typedef __attribute__((ext_vector_type(2))) __bf16 bf16x2;
typedef __attribute__((ext_vector_type(4))) float f32x4;
typedef __attribute__((ext_vector_type(2))) float f32x2;

struct PtrsV { const void* p[8]; };

// ---------------------------------------------------------------------------
// Dtype detection (verified R2-R6) + deg zeroing. flags 1 = fp32, 0 = bf16.
// ---------------------------------------------------------------------------
__device__ __forceinline__ int bf16_wild(unsigned short w) {
    int exp = (w >> 7) & 0xFF;
    int mant = w & 0x7F;
    if (exp == 0xFF) return 1;
    if (exp >= 133) return 1;                // |x| >= 64
    if (exp == 0) return mant != 0 ? 1 : 0;  // denormal
    if (exp <= 114) return 1;                // 0 < |x| < 2^-12
    return 0;
}

__global__ void __launch_bounds__(256) detect_zero_kernel(
    const unsigned short* __restrict__ emb,
    const unsigned short* __restrict__ w,
    const unsigned short* __restrict__ b,
    const unsigned short* __restrict__ hc,
    int* __restrict__ flags, int* __restrict__ deg)
{
    if (blockIdx.x == 0) {
        int lane = threadIdx.x;
        if (lane >= 64) return;
        int ce = 0, cw = 0, cb = 0, ch = 0;
        for (int j = 0; j < 4; ++j) {
            ce += bf16_wild(emb[lane * 4 + j]);
            cw += bf16_wild(w[lane * 4 + j]);
        }
        for (int j = 0; j < 2; ++j) cb += bf16_wild(b[lane * 2 + j]);
        if (lane < 3) ch = bf16_wild(hc[lane]);
        for (int off = 32; off > 0; off >>= 1) {
            ce += __shfl_down(ce, off);
            cw += __shfl_down(cw, off);
            cb += __shfl_down(cb, off);
            ch += __shfl_down(ch, off);
        }
        if (lane == 0) {
            int wf = (cw >= 16) ? 1 : 0;
            flags[0] = (ce >= 16) ? 1 : 0;
            flags[1] = wf;
            flags[2] = (cb >= 8) ? 1 : 0;
            flags[3] = (ch > 0) ? 1 : wf;
        }
    } else {
        int i = (blockIdx.x - 1) * 256 + threadIdx.x;
        if (i < N_NODES) deg[i] = 0;
    }
}

// ---------------------------------------------------------------------------
// Pack weights into MFMA B-fragment order (verified R2-R6).
// Frag index within matrix (as bf16x8): kk*512 + n0*64 + lane.
// Slots 4,5 are the second hh matrix (+16384 elems / +128 bias).
// ---------------------------------------------------------------------------
__global__ void __launch_bounds__(256) pack_kernel(
    PtrsV wmats, PtrsV bvecs, const void* hc_raw,
    const int* __restrict__ flags,
    bf16* __restrict__ pw, float* __restrict__ cbias, float* __restrict__ ccoef)
{
    int tid = blockIdx.x * 256 + threadIdx.x;
    int wf = flags[1], bfl = flags[2], hf = flags[3];
    if (tid < 8 * 16384) {
        int m    = tid >> 14;
        int r    = tid & 16383;
        int j    = r & 7;
        int lane = (r >> 3) & 63;
        int n0   = (r >> 9) & 7;
        int kk   = r >> 12;
        int k = kk * 32 + (lane >> 4) * 8 + j;
        int n = n0 * 16 + (lane & 15);
        int idx = k * C + n + ((m == 4 || m == 5) ? 16384 : 0);
        float v = wf ? ((const float*)wmats.p[m])[idx]
                     : (float)((const bf16*)wmats.p[m])[idx];
        pw[tid] = (bf16)v;
    } else if (tid < 8 * 16384 + 1024) {
        int j = tid - 8 * 16384;
        int m = j >> 7, n = j & 127;
        int idx = n + ((m == 4 || m == 5) ? 128 : 0);
        float v = bfl ? ((const float*)bvecs.p[m])[idx]
                      : (float)((const bf16*)bvecs.p[m])[idx];
        cbias[j] = v;
    } else if (tid < 8 * 16384 + 1024 + 3) {
        int i = tid - (8 * 16384 + 1024);
        float v = hf ? ((const float*)hc_raw)[i]
                     : (float)((const bf16*)hc_raw)[i];
        ccoef[i] = v;
    }
}

// ---------------------------------------------------------------------------
// MLP v4: per-wave 64-node group (4 strips of 16). B-fragments loaded once
// per weight column-block and applied to 4 strips -> B traffic /4 vs R5.
// No barriers; in-wave LDS round-trip for the GEMM1->GEMM2 layout transform
// (pattern verified R3/R5). launch_bounds(256,2): VGPR cap 256, 8 waves/CU.
// ---------------------------------------------------------------------------
__global__ __launch_bounds__(256, 2) void mlp_kernel(
    const void* __restrict__ emb_raw,    // [3][N][C] fp32 or bf16
    const bf16* __restrict__ pw,         // packed weights [8][16384]
    const float* __restrict__ cbias,     // [8][128]
    const float* __restrict__ ccoef,     // [3]
    const int* __restrict__ flags,
    bf16* __restrict__ h,                // [3][N][C], premultiplied by coef
    bf16* __restrict__ hs)               // [N][C] self term (loop MLP)
{
    __shared__ bf16 sH[4][64][136];      // 69.6 KB -> 2 blocks/CU
    const int tid  = threadIdx.x;
    const int wave = tid >> 6, lane = tid & 63;
    const int wid  = blockIdx.x * 4 + wave;     // 0..3127
    if (wid >= N_TASKS * GROUPS) return;
    const int task = wid & 3;
    const int grp  = wid >> 2;                  // 0..781
    const int lrow = lane & 15, lquad = lane >> 4;
    bf16 (*sh)[136] = sH[wave];

    const int m1_of[4] = {0, 2, 4, 6};
    const int ly_of[4] = {2, 1, 0, 2};
    const int m1 = m1_of[task];
    const bf16x8* w1v = (const bf16x8*)(pw + (size_t)m1 * 16384);
    const bf16x8* w2v = w1v + 2048;
    const float oscale = (task == 0) ? ccoef[0] : (task == 1) ? ccoef[1]
                       : (task == 2) ? ccoef[2] : 1.0f;
    bf16* outp = (task == 3) ? hs : (h + (size_t)task * N_NODES * C);
    const int emb_f32 = flags[0];
    const size_t lbase = (size_t)ly_of[task] * N_NODES * C;

    const int s0 = grp * 4;
    int nv = STRIPS - s0; if (nv > 4) nv = 4;   // valid strips (uniform per wave)

    // ---- biases for this lane's columns ----
    float b1f[8], b2f[8];
    #pragma unroll
    for (int n0 = 0; n0 < 8; ++n0) {
        b1f[n0] = cbias[m1 * 128 + n0 * 16 + lrow];
        b2f[n0] = cbias[(m1 + 1) * 128 + n0 * 16 + lrow];
    }

    // ---- A-fragments for up to 4 strips, direct from global ----
    // A[m=lane&15][k=quad*8+j] per strip.
    bf16x8 af[4][4];
    #pragma unroll
    for (int i = 0; i < 4; ++i) {
        if (i < nv) {
            size_t xb = lbase + (size_t)((s0 + i) * 16 + lrow) * C + lquad * 8;
            if (emb_f32) {
                const float* xf = (const float*)emb_raw + xb;
                #pragma unroll
                for (int kk = 0; kk < 4; ++kk) {
                    f32x4 u0 = *(const f32x4*)(xf + kk * 32);
                    f32x4 u1 = *(const f32x4*)(xf + kk * 32 + 4);
                    bf16x8 v;
                    v[0]=(bf16)u0[0]; v[1]=(bf16)u0[1]; v[2]=(bf16)u0[2]; v[3]=(bf16)u0[3];
                    v[4]=(bf16)u1[0]; v[5]=(bf16)u1[1]; v[6]=(bf16)u1[2]; v[7]=(bf16)u1[3];
                    af[i][kk] = v;
                }
            } else {
                const bf16* x16 = (const bf16*)emb_raw + xb;
                #pragma unroll
                for (int kk = 0; kk < 4; ++kk)
                    af[i][kk] = *(const bf16x8*)(x16 + kk * 32);
            }
        }
    }

    // ---- GEMM1: hidden = relu(X @ W1 + b1) -> sh, B loaded once per n0 ----
    #pragma unroll
    for (int n0 = 0; n0 < 8; ++n0) {
        bf16x8 bv0 = w1v[0 * 512 + n0 * 64 + lane];
        bf16x8 bv1 = w1v[1 * 512 + n0 * 64 + lane];
        bf16x8 bv2 = w1v[2 * 512 + n0 * 64 + lane];
        bf16x8 bv3 = w1v[3 * 512 + n0 * 64 + lane];
        int n = n0 * 16 + lrow;
        float bias = b1f[n0];
        #pragma unroll
        for (int i = 0; i < 4; ++i) {
            if (i < nv) {
                f32x4 a4 = {0.f, 0.f, 0.f, 0.f};
                a4 = __builtin_amdgcn_mfma_f32_16x16x32_bf16(af[i][0], bv0, a4, 0, 0, 0);
                a4 = __builtin_amdgcn_mfma_f32_16x16x32_bf16(af[i][1], bv1, a4, 0, 0, 0);
                a4 = __builtin_amdgcn_mfma_f32_16x16x32_bf16(af[i][2], bv2, a4, 0, 0, 0);
                a4 = __builtin_amdgcn_mfma_f32_16x16x32_bf16(af[i][3], bv3, a4, 0, 0, 0);
                #pragma unroll
                for (int r = 0; r < 4; ++r) {
                    float v = a4[r] + bias;
                    v = v > 0.f ? v : 0.f;
                    sh[i * 16 + lquad * 4 + r][n] = (bf16)v;
                }
            }
        }
    }

    // ---- read ALL GEMM2 A-frags (then sh is free to overwrite) ----
    bf16x8 ah[4][4];
    #pragma unroll
    for (int i = 0; i < 4; ++i)
        if (i < nv) {
            #pragma unroll
            for (int kk = 0; kk < 4; ++kk)
                ah[i][kk] = *(const bf16x8*)(&sh[i * 16 + lrow][kk * 32 + lquad * 8]);
        }

    // ---- GEMM2: out = oscale*(hidden @ W2 + b2) -> sh ----
    #pragma unroll
    for (int n0 = 0; n0 < 8; ++n0) {
        bf16x8 bv0 = w2v[0 * 512 + n0 * 64 + lane];
        bf16x8 bv1 = w2v[1 * 512 + n0 * 64 + lane];
        bf16x8 bv2 = w2v[2 * 512 + n0 * 64 + lane];
        bf16x8 bv3 = w2v[3 * 512 + n0 * 64 + lane];
        int n = n0 * 16 + lrow;
        float bias = b2f[n0];
        #pragma unroll
        for (int i = 0; i < 4; ++i) {
            if (i < nv) {
                f32x4 a4 = {0.f, 0.f, 0.f, 0.f};
                a4 = __builtin_amdgcn_mfma_f32_16x16x32_bf16(ah[i][0], bv0, a4, 0, 0, 0);
                a4 = __builtin_amdgcn_mfma_f32_16x16x32_bf16(ah[i][1], bv1, a4, 0, 0, 0);
                a4 = __builtin_amdgcn_mfma_f32_16x16x32_bf16(ah[i][2], bv2, a4, 0, 0, 0);
                a4 = __builtin_amdgcn_mfma_f32_16x16x32_bf16(ah[i][3], bv3, a4, 0, 0, 0);
                #pragma unroll
                for (int r = 0; r < 4; ++r)
                    sh[i * 16 + lquad * 4 + r][n] = (bf16)((a4[r] + bias) * oscale);
            }
        }
    }

    // ---- coalesced store of up to 64 rows ----
    {
        int row = lane >> 2;
        int cs  = (lane & 3) * 32;
        #pragma unroll
        for (int i = 0; i < 4; ++i) {
            if (i < nv) {
                bf16* dst = outp + (size_t)((s0 + i) * 16) * C;
                #pragma unroll
                for (int j = 0; j < 4; ++j) {
                    bf16x8 v = *(const bf16x8*)(&sh[i * 16 + row][cs + j * 8]);
                    *(bf16x8*)(dst + (size_t)row * C + cs + j * 8) = v;
                }
            }
        }
    }
}

// ---------------------------------------------------------------------------
// CSR build: histogram, 3-phase scan, bucket fill (verified R5/R6).
// ---------------------------------------------------------------------------
__global__ void __launch_bounds__(256) hist_kernel(
    const int* __restrict__ erow, int* __restrict__ deg)
{
    int e = blockIdx.x * 256 + threadIdx.x;
    if (e >= N_EDGES) return;
    atomicAdd(&deg[erow[e]], 1);
}

__device__ __forceinline__ int wave_incl_scan(int v, int lane) {
    int x = v;
    #pragma unroll
    for (int d = 1; d < 64; d <<= 1) {
        int t = __shfl_up(x, d);
        if (lane >= d) x += t;
    }
    return x;
}

__global__ void __launch_bounds__(256) scanA_kernel(
    const int* __restrict__ deg, int* __restrict__ offsets, int* __restrict__ btot)
{
    __shared__ int swave[4];
    int b = blockIdx.x, tid = threadIdx.x;
    int i = b * 256 + tid;
    int lane = tid & 63, wv = tid >> 6;
    int v = (i < N_NODES) ? deg[i] : 0;
    int x = wave_incl_scan(v, lane);
    if (lane == 63) swave[wv] = x;
    __syncthreads();
    int w0 = swave[0], w1 = swave[1], w2 = swave[2], w3 = swave[3];
    int wp = (wv > 0 ? w0 : 0) + (wv > 1 ? w1 : 0) + (wv > 2 ? w2 : 0);
    if (i < N_NODES) offsets[i] = wp + x - v;
    if (tid == 0) btot[b] = w0 + w1 + w2 + w3;
}

__global__ void __launch_bounds__(256) scanB_kernel(
    const int* __restrict__ btot, int* __restrict__ bbase, int nblk)
{
    __shared__ int swave[4];
    int tid = threadIdx.x;
    int lane = tid & 63, wv = tid >> 6;
    int v = (tid < nblk) ? btot[tid] : 0;
    int x = wave_incl_scan(v, lane);
    if (lane == 63) swave[wv] = x;
    __syncthreads();
    int w0 = swave[0], w1 = swave[1], w2 = swave[2], w3 = swave[3];
    int wp = (wv > 0 ? w0 : 0) + (wv > 1 ? w1 : 0) + (wv > 2 ? w2 : 0);
    if (tid < nblk) bbase[tid] = wp + x - v;
}

__global__ void __launch_bounds__(256) scanC_kernel(
    const int* __restrict__ bbase, int* __restrict__ offsets, int* __restrict__ cursor)
{
    int i = blockIdx.x * 256 + threadIdx.x;
    if (i < N_NODES) {
        int o = offsets[i] + bbase[blockIdx.x];
        offsets[i] = o;
        cursor[i] = o;
    }
    if (i == 0) offsets[N_NODES] = N_EDGES;
}

__global__ void __launch_bounds__(256) fill_kernel(
    const int* __restrict__ erow, const int* __restrict__ ecol,
    const int* __restrict__ ew,
    int* __restrict__ cursor, int* __restrict__ edata)
{
    int e = blockIdx.x * 256 + threadIdx.x;
    if (e >= N_EDGES) return;
    int dst = erow[e];
    int pos = atomicAdd(&cursor[dst], 1);
    edata[pos] = (ecol[e] << 2) | (ew[e] - 1);
}

// ---------------------------------------------------------------------------
// Gather: one wave per node, lane = 2 channels; h coef-premultiplied so the
// inner op is a plain add. 8/4/1 unroll cascade for load ILP.
// ---------------------------------------------------------------------------
__global__ void __launch_bounds__(256) gather_kernel(
    const int* __restrict__ offsets, const int* __restrict__ edata,
    const bf16* __restrict__ h,          // [3][N][C]
    const bf16* __restrict__ hs,         // [N][C]
    void* __restrict__ out,
    const int* __restrict__ flags)
{
    const int node = blockIdx.x * 4 + (threadIdx.x >> 6);
    if (node >= N_NODES) return;
    const int lane = threadIdx.x & 63;
    const int c = lane * 2;

    bf16x2 sv = *(const bf16x2*)(hs + (size_t)node * C + c);
    float a0 = (float)sv[0], a1 = (float)sv[1];

    const int s = offsets[node], e = offsets[node + 1];
    for (int base = s; base < e; base += 64) {
        int idx = base + lane;
        int ed_i = (idx < e) ? edata[idx] : 0;
        int cnt = e - base; if (cnt > 64) cnt = 64;
        int j = 0;
        for (; j + 8 <= cnt; j += 8) {
            float t0 = 0.f, t1 = 0.f;
            #pragma unroll
            for (int u = 0; u < 8; ++u) {
                int ed = __shfl(ed_i, j + u);
                bf16x2 v = *(const bf16x2*)(h + (size_t)(ed & 3) * (N_NODES * C)
                                              + (size_t)(ed >> 2) * C + c);
                t0 += (float)v[0];
                t1 += (float)v[1];
            }
            a0 += t0; a1 += t1;
        }
        for (; j + 4 <= cnt; j += 4) {
            int e0 = __shfl(ed_i, j);
            int e1 = __shfl(ed_i, j + 1);
            int e2 = __shfl(ed_i, j + 2);
            int e3 = __shfl(ed_i, j + 3);
            bf16x2 v0 = *(const bf16x2*)(h + (size_t)(e0 & 3) * (N_NODES * C) + (size_t)(e0 >> 2) * C + c);
            bf16x2 v1 = *(const bf16x2*)(h + (size_t)(e1 & 3) * (N_NODES * C) + (size_t)(e1 >> 2) * C + c);
            bf16x2 v2 = *(const bf16x2*)(h + (size_t)(e2 & 3) * (N_NODES * C) + (size_t)(e2 >> 2) * C + c);
            bf16x2 v3 = *(const bf16x2*)(h + (size_t)(e3 & 3) * (N_NODES * C) + (size_t)(e3 >> 2) * C + c);
            a0 += (float)v0[0] + (float)v1[0] + (float)v2[0] + (float)v3[0];
            a1 += (float)v0[1] + (float)v1[1] + (float)v2[1] + (float)v3[1];
        }
        for (; j < cnt; ++j) {
            int ed = __shfl(ed_i, j);
            bf16x2 v = *(const bf16x2*)(h + (size_t)(ed & 3) * (N_NODES * C) + (size_t)(ed >> 2) * C + c);
            a0 += (float)v[0];
            a1 += (float)v[1];
        }
    }

    if (flags[0]) {
        f32x2 o; o[0] = a0; o[1] = a1;
        *(f32x2*)((float*)out + (size_t)node * C + c) = o;
    } else {
        bf16x2 o; o[0] = (bf16)a0; o[1] = (bf16)a1;
        *(bf16x2*)((bf16*)out + (size_t)node * C + c) = o;
    }
}

// ---------------------------------------------------------------------------
extern "C" void kernel_launch(void* const* d_in, const int* in_sizes, int n_in,
                              void* d_out, int out_size, void* d_ws, size_t ws_size,
                              hipStream_t stream) {
    // 0 t | 1 node_embeddings [3,N,C] | 2 edge_index [2,E] | 3 edge_weights [E]
    // 4 loop_W1 5 loop_b1 6 loop_W2 7 loop_b2 | 8 rel_W1 9 rel_b1 10 rel_W2 11 rel_b2
    // 12 hh_W1 [2,C,C] 13 hh_b1 [2,C] 14 hh_W2 [2,C,C] 15 hh_b2 [2,C] | 16 hop_coef [3]
    const void* emb = d_in[1];
    const int*  ei  = (const int*)d_in[2];
    const int*  ew  = (const int*)d_in[3];

    // ws layout
    const size_t H_BYTES  = (size_t)3 * N_NODES * C * sizeof(bf16);   // 38.4 MB
    const size_t HS_BYTES = (size_t)N_NODES * C * sizeof(bf16);       // 12.8 MB
    const size_t PW_BYTES = (size_t)8 * 16384 * sizeof(bf16);         // 256 KB
    bf16*  h      = (bf16*)d_ws;
    bf16*  hs     = (bf16*)((char*)d_ws + H_BYTES);
    bf16*  pw     = (bf16*)((char*)d_ws + H_BYTES + HS_BYTES);
    float* cbias  = (float*)((char*)d_ws + H_BYTES + HS_BYTES + PW_BYTES);
    float* ccoef  = cbias + 1024;
    int*   flags  = (int*)(ccoef + 4);
    int*   deg    = flags + 16;
    int*   cursor = deg + N_NODES;
    int*   offsets= cursor + N_NODES;
    int*   btot   = offsets + N_NODES + 8;
    int*   bbase  = btot + 256;
    int*   edata  = bbase + 256;

    // pack slots: 0 rel_W1, 1 rel_W2, 2 hh_W1[0], 3 hh_W2[0], 4 hh_W1[1], 5 hh_W2[1], 6 loop_W1, 7 loop_W2
    PtrsV wptr;
    wptr.p[0] = d_in[8];   wptr.p[1] = d_in[10];
    wptr.p[2] = d_in[12];  wptr.p[3] = d_in[14];
    wptr.p[4] = d_in[12];  wptr.p[5] = d_in[14];   // +16384 elems inside pack
    wptr.p[6] = d_in[4];   wptr.p[7] = d_in[6];
    PtrsV bptr;
    bptr.p[0] = d_in[9];   bptr.p[1] = d_in[11];
    bptr.p[2] = d_in[13];  bptr.p[3] = d_in[15];
    bptr.p[4] = d_in[13];  bptr.p[5] = d_in[15];   // +128 inside pack
    bptr.p[6] = d_in[5];   bptr.p[7] = d_in[7];

    const int NBLK = (N_NODES + 255) / 256;   // 196

    detect_zero_kernel<<<1 + NBLK, 256, 0, stream>>>(
        (const unsigned short*)emb, (const unsigned short*)d_in[8],
        (const unsigned short*)d_in[9], (const unsigned short*)d_in[16],
        flags, deg);

    pack_kernel<<<517, 256, 0, stream>>>(wptr, bptr, d_in[16], flags, pw, cbias, ccoef);

    const int* erow = ei;
    const int* ecol = ei + N_EDGES;
    hist_kernel<<<(N_EDGES + 255) / 256, 256, 0, stream>>>(erow, deg);
    scanA_kernel<<<NBLK, 256, 0, stream>>>(deg, offsets, btot);
    scanB_kernel<<<1, 256, 0, stream>>>(btot, bbase, NBLK);
    scanC_kernel<<<NBLK, 256, 0, stream>>>(bbase, offsets, cursor);
    fill_kernel<<<(N_EDGES + 255) / 256, 256, 0, stream>>>(erow, ecol, ew, cursor, edata);

    // MLPs: 4 tasks x 782 groups of 64 nodes, one wave per group
    mlp_kernel<<<(N_TASKS * GROUPS + 3) / 4, 256, 0, stream>>>(
        emb, pw, cbias, ccoef, flags, h, hs);

    gather_kernel<<<(N_NODES + 3) / 4, 256, 0, stream>>>(
        offsets, edata, h, hs, d_out, flags);
}